// Round 1
// baseline (818.695 us; speedup 1.0000x reference)
//
#include <hip/hip_runtime.h>
#include <hip/hip_bf16.h>
#include <math.h>

typedef __attribute__((ext_vector_type(8))) short bf16x8;
typedef __attribute__((ext_vector_type(4))) float f32x4;

static __device__ __forceinline__ short f2bf(float f) {
    union { float f; unsigned u; } a; a.f = f;
    unsigned r = 0x7FFFu + ((a.u >> 16) & 1u);
    return (short)((a.u + r) >> 16);
}
static __device__ __forceinline__ float bf2f(short s) {
    union { unsigned u; float f; } a;
    a.u = ((unsigned)(unsigned short)s) << 16;
    return a.f;
}

// ---------------------------------------------------------------------------
// Weight transpose: W (c,d) fp32 -> WT (d,c) bf16, 4 weights stacked in z.
// ---------------------------------------------------------------------------
__global__ __launch_bounds__(256)
void transpose_w(const float* __restrict__ w0, const float* __restrict__ w1,
                 const float* __restrict__ w2, const float* __restrict__ w3,
                 short* __restrict__ outT)
{
    __shared__ float ld[32][33];
    const float* W = (blockIdx.z == 0) ? w0 : (blockIdx.z == 1) ? w1
                   : (blockIdx.z == 2) ? w2 : w3;
    short* O = outT + (long long)blockIdx.z * 512 * 512;
    const int tx = threadIdx.x & 31, ty = threadIdx.x >> 5;
    const int c0 = blockIdx.y * 32, d0 = blockIdx.x * 32;
#pragma unroll
    for (int r = 0; r < 4; ++r)
        ld[ty + 8 * r][tx] = W[(long long)(c0 + ty + 8 * r) * 512 + d0 + tx];
    __syncthreads();
#pragma unroll
    for (int r = 0; r < 4; ++r)
        O[(long long)(d0 + ty + 8 * r) * 512 + c0 + tx] = f2bf(ld[tx][ty + 8 * r]);
}

// ---------------------------------------------------------------------------
// GroupNorm stats: one block per (b,g); group = 16 channels x 1024 spatial,
// contiguous 16384 floats. Writes (mean, rstd).
// ---------------------------------------------------------------------------
__global__ __launch_bounds__(256)
void gn_stats(const float* __restrict__ x, float2* __restrict__ stats)
{
    const int bg = blockIdx.x;
    const float4* p = reinterpret_cast<const float4*>(x + (long long)bg * 16384);
    float s = 0.f, ss = 0.f;
    for (int i = threadIdx.x; i < 4096; i += 256) {
        float4 v = p[i];
        s  += v.x + v.y + v.z + v.w;
        ss += v.x * v.x + v.y * v.y + v.z * v.z + v.w * v.w;
    }
    __shared__ float rs[256], rss[256];
    rs[threadIdx.x] = s; rss[threadIdx.x] = ss;
    __syncthreads();
    for (int o = 128; o > 0; o >>= 1) {
        if (threadIdx.x < o) { rs[threadIdx.x] += rs[threadIdx.x + o];
                               rss[threadIdx.x] += rss[threadIdx.x + o]; }
        __syncthreads();
    }
    if (threadIdx.x == 0) {
        float mean = rs[0] * (1.f / 16384.f);
        float var  = rss[0] * (1.f / 16384.f) - mean * mean;
        stats[bg] = make_float2(mean, rsqrtf(var + 1e-6f));
    }
}

// ---------------------------------------------------------------------------
// GroupNorm apply + transpose: x (b,c,s) fp32 -> hn (b,s,c) bf16.
// One block handles 32 s x 512 c, LDS-transposed for coalesced writes.
// ---------------------------------------------------------------------------
__global__ __launch_bounds__(256)
void gn_apply_t(const float* __restrict__ x, const float2* __restrict__ stats,
                const float* __restrict__ gamma, const float* __restrict__ beta,
                short* __restrict__ hn)
{
    __shared__ short lds[32 * 520];  // 32 s-rows x 512 c + 8 pad (16B) per row
    const int t = threadIdx.x;
    const int s0 = blockIdx.x * 32;
    const int b  = blockIdx.y;
#pragma unroll
    for (int i = 0; i < 16; ++i) {
        int qi = t + 256 * i;          // 0..4095
        int c = qi >> 3, sc = qi & 7;  // c 0..511, sc = 4-float chunk within 32 s
        float4 v = *reinterpret_cast<const float4*>(
            x + ((long long)(b * 512 + c)) * 1024 + s0 + sc * 4);
        float2 st = stats[b * 32 + (c >> 4)];
        float ga = gamma[c], be = beta[c];
        float m = st.x, r = st.y;
        lds[(sc * 4 + 0) * 520 + c] = f2bf((v.x - m) * r * ga + be);
        lds[(sc * 4 + 1) * 520 + c] = f2bf((v.y - m) * r * ga + be);
        lds[(sc * 4 + 2) * 520 + c] = f2bf((v.z - m) * r * ga + be);
        lds[(sc * 4 + 3) * 520 + c] = f2bf((v.w - m) * r * ga + be);
    }
    __syncthreads();
#pragma unroll
    for (int i = 0; i < 8; ++i) {
        int p = t + 256 * i;           // 0..2047
        int s = p >> 6, j = p & 63;    // 16B chunk j within 1KB c-row
        float4 v = *reinterpret_cast<const float4*>(&lds[s * 520 + j * 8]);
        *reinterpret_cast<float4*>(
            hn + ((long long)(b * 1024 + s0 + s)) * 512 + j * 8) = v;
    }
}

// ---------------------------------------------------------------------------
// NT GEMM: C[m,n] = (sum_k A[m,k]*B[n,k] + biasM[m] + biasN[n]) * scale
//          (+ resid, fp32 out) — both operands row-major K-contiguous bf16.
// BM=BN=128, BK=64, 256 threads (4 waves), each wave 64x64 via 16x16x32 MFMA.
// ---------------------------------------------------------------------------
template<int BIAS_M, int BIAS_N, int RESID>
__global__ __launch_bounds__(256)
void nt_gemm(const short* __restrict__ A, const short* __restrict__ B,
             void* __restrict__ Cv,
             const float* __restrict__ biasM, const float* __restrict__ biasN,
             const float* __restrict__ resid,
             float scale, int M, int N, int K,
             int lda, int ldb, int ldc,
             long long sA, long long sB, long long sC)
{
    __shared__ short lsA[128 * 72];   // 64 bf16 + 8 pad per row (144B rows)
    __shared__ short lsB[128 * 72];
    const int t = threadIdx.x;
    const int bz = blockIdx.z;
    const int m0 = blockIdx.y * 128;
    const int n0 = blockIdx.x * 128;
    const int lane = t & 63;
    const int w = t >> 6;
    const int wr = w >> 1, wc = w & 1;
    const int lr16 = lane & 15, lkg = lane >> 4;

    const int tr  = t >> 3;   // staging row base 0..31 (rows tr+32i)
    const int tkc = t & 7;    // 16B chunk within 128B row

    const short* Ap = A + (long long)bz * sA + (long long)(m0 + tr) * lda + tkc * 8;
    const short* Bp = B + (long long)bz * sB + (long long)(n0 + tr) * ldb + tkc * 8;

    f32x4 acc[4][4];
#pragma unroll
    for (int i = 0; i < 4; ++i)
#pragma unroll
        for (int j = 0; j < 4; ++j) acc[i][j] = (f32x4){0.f, 0.f, 0.f, 0.f};

    float4 ra[4], rb[4];
#pragma unroll
    for (int i = 0; i < 4; ++i) {
        ra[i] = *reinterpret_cast<const float4*>(Ap + (long long)(32 * i) * lda);
        rb[i] = *reinterpret_cast<const float4*>(Bp + (long long)(32 * i) * ldb);
    }

    const int nk = K >> 6;
    for (int kt = 0; kt < nk; ++kt) {
#pragma unroll
        for (int i = 0; i < 4; ++i) {
            *reinterpret_cast<float4*>(&lsA[(tr + 32 * i) * 72 + tkc * 8]) = ra[i];
            *reinterpret_cast<float4*>(&lsB[(tr + 32 * i) * 72 + tkc * 8]) = rb[i];
        }
        __syncthreads();
        if (kt + 1 < nk) {  // prefetch next K-tile under the MFMAs
#pragma unroll
            for (int i = 0; i < 4; ++i) {
                ra[i] = *reinterpret_cast<const float4*>(
                    Ap + (long long)(32 * i) * lda + (kt + 1) * 64);
                rb[i] = *reinterpret_cast<const float4*>(
                    Bp + (long long)(32 * i) * ldb + (kt + 1) * 64);
            }
        }
#pragma unroll
        for (int ks = 0; ks < 2; ++ks) {
            bf16x8 af[4], bfr[4];
#pragma unroll
            for (int mi = 0; mi < 4; ++mi)
                af[mi] = *reinterpret_cast<const bf16x8*>(
                    &lsA[(wr * 64 + mi * 16 + lr16) * 72 + ks * 32 + lkg * 8]);
#pragma unroll
            for (int ni = 0; ni < 4; ++ni)
                bfr[ni] = *reinterpret_cast<const bf16x8*>(
                    &lsB[(wc * 64 + ni * 16 + lr16) * 72 + ks * 32 + lkg * 8]);
#pragma unroll
            for (int mi = 0; mi < 4; ++mi)
#pragma unroll
                for (int ni = 0; ni < 4; ++ni)
                    acc[mi][ni] = __builtin_amdgcn_mfma_f32_16x16x32_bf16(
                        af[mi], bfr[ni], acc[mi][ni], 0, 0, 0);
        }
        __syncthreads();
    }

    // epilogue: D layout col=lane&15, row=(lane>>4)*4+reg (m89-verified)
#pragma unroll
    for (int mi = 0; mi < 4; ++mi) {
#pragma unroll
        for (int ni = 0; ni < 4; ++ni) {
            const int col = n0 + wc * 64 + ni * 16 + lr16;
            float bn = 0.f;
            if (BIAS_N) bn = biasN[col];
#pragma unroll
            for (int j = 0; j < 4; ++j) {
                const int rrow = m0 + wr * 64 + mi * 16 + lkg * 4 + j;
                float v = acc[mi][ni][j];
                if (BIAS_M) v += biasM[rrow];
                if (BIAS_N) v += bn;
                v *= scale;
                const long long idx = (long long)rrow * ldc + col;
                if (RESID) {
                    float* Cf = (float*)Cv + (long long)bz * sC;
                    Cf[idx] = v + resid[(long long)bz * sC + idx];
                } else {
                    short* Cs = (short*)Cv + (long long)bz * sC;
                    Cs[idx] = f2bf(v);
                }
            }
        }
    }
}

// ---------------------------------------------------------------------------
// Row softmax over 1024 bf16, in place. One wave per row, 4 rows per block.
// ---------------------------------------------------------------------------
__global__ __launch_bounds__(256)
void softmax_rows(short* __restrict__ S)
{
    const int wave = threadIdx.x >> 6, lane = threadIdx.x & 63;
    const long long row = (long long)blockIdx.x * 4 + wave;
    short* p = S + row * 1024;
    bf16x8 h0 = *reinterpret_cast<bf16x8*>(p + lane * 8);
    bf16x8 h1 = *reinterpret_cast<bf16x8*>(p + 512 + lane * 8);
    float v[16];
#pragma unroll
    for (int j = 0; j < 8; ++j) { v[j] = bf2f(h0[j]); v[8 + j] = bf2f(h1[j]); }
    float m = -1e30f;
#pragma unroll
    for (int j = 0; j < 16; ++j) m = fmaxf(m, v[j]);
#pragma unroll
    for (int o = 32; o > 0; o >>= 1) m = fmaxf(m, __shfl_xor(m, o));
    float s = 0.f;
#pragma unroll
    for (int j = 0; j < 16; ++j) { v[j] = __expf(v[j] - m); s += v[j]; }
#pragma unroll
    for (int o = 32; o > 0; o >>= 1) s += __shfl_xor(s, o);
    const float inv = 1.f / s;
    bf16x8 o0, o1;
#pragma unroll
    for (int j = 0; j < 8; ++j) { o0[j] = f2bf(v[j] * inv); o1[j] = f2bf(v[8 + j] * inv); }
    *reinterpret_cast<bf16x8*>(p + lane * 8) = o0;
    *reinterpret_cast<bf16x8*>(p + 512 + lane * 8) = o1;
}

// ---------------------------------------------------------------------------
extern "C" void kernel_launch(void* const* d_in, const int* in_sizes, int n_in,
                              void* d_out, int out_size, void* d_ws, size_t ws_size,
                              hipStream_t stream)
{
    (void)in_sizes; (void)n_in; (void)out_size; (void)ws_size;
    const float* x     = (const float*)d_in[0];
    const float* gamma = (const float*)d_in[1];
    const float* beta  = (const float*)d_in[2];
    const float* Wq = (const float*)d_in[3];
    const float* bq = (const float*)d_in[4];
    const float* Wk = (const float*)d_in[5];
    const float* bk = (const float*)d_in[6];
    const float* Wv = (const float*)d_in[7];
    const float* bv = (const float*)d_in[8];
    const float* Wp = (const float*)d_in[9];
    const float* bp = (const float*)d_in[10];
    float* out = (float*)d_out;

    // Workspace layout (time-overlapped): total ~162.1 MB
    //   [0,64M):   S/P (b,s,t) bf16; hn (b,s,c) bf16 lives in [0,32M) and
    //              dies (last read: v-GEMM) before S is written (scores-GEMM).
    //   [64,96M):  q (b,s,c) bf16; reused as h_out (b,s,c) after scores.
    //   [96,128M): k (b,s,c) bf16
    //   [128,160M):v (b,c,t) bf16
    //   [160M..):  WqT/WkT/WvT/WpT (d,c) bf16 (2MB) ; stats (8KB)
    char* ws = (char*)d_ws;
    short*  S  = (short*)ws;
    short*  hn = (short*)ws;
    short*  q  = (short*)(ws + (64LL << 20));
    short*  k  = (short*)(ws + (96LL << 20));
    short*  v  = (short*)(ws + (128LL << 20));
    short*  wT = (short*)(ws + (160LL << 20));
    float2* stats = (float2*)(ws + (162LL << 20));
    short*  ho = q;  // alias: h_out replaces q after the scores GEMM

    const short* WqT = wT;
    const short* WkT = wT + 512 * 512;
    const short* WvT = wT + 2 * 512 * 512;
    const short* WpT = wT + 3 * 512 * 512;

    transpose_w<<<dim3(16, 16, 4), 256, 0, stream>>>(Wq, Wk, Wv, Wp, wT);
    gn_stats<<<dim3(1024), 256, 0, stream>>>(x, stats);
    gn_apply_t<<<dim3(32, 32), 256, 0, stream>>>(x, stats, gamma, beta, hn);

    const float qscale = 0.044194173824159216f;  // 512^-0.5

    // q = (hn @ Wq + bq) * scale : M=s=1024, N=d=512, K=c=512
    nt_gemm<0, 1, 0><<<dim3(4, 8, 32), 256, 0, stream>>>(
        hn, WqT, q, nullptr, bq, nullptr, qscale,
        1024, 512, 512, 512, 512, 512, 1024 * 512, 0, 1024 * 512);
    // k = hn @ Wk + bk
    nt_gemm<0, 1, 0><<<dim3(4, 8, 32), 256, 0, stream>>>(
        hn, WkT, k, nullptr, bk, nullptr, 1.f,
        1024, 512, 512, 512, 512, 512, 1024 * 512, 0, 1024 * 512);
    // v (d,t) = WvT @ hn^T + bv : M=d=512, N=t=1024, K=c=512
    nt_gemm<1, 0, 0><<<dim3(8, 4, 32), 256, 0, stream>>>(
        WvT, hn, v, bv, nullptr, nullptr, 1.f,
        512, 1024, 512, 512, 512, 1024, 0, 1024 * 512, 512 * 1024);
    // scores (s,t) = q @ k^T : M=N=1024, K=512   (scale already folded into q)
    nt_gemm<0, 0, 0><<<dim3(8, 8, 32), 256, 0, stream>>>(
        q, k, S, nullptr, nullptr, nullptr, 1.f,
        1024, 1024, 512, 512, 512, 1024, 1024 * 512, 1024 * 512, 1024LL * 1024);
    // P = softmax(S) rowwise, in place
    softmax_rows<<<dim3(8192), 256, 0, stream>>>(S);
    // h_out (s,c) = P @ v^T : M=s=1024, N=c=512, K=t=1024
    nt_gemm<0, 0, 0><<<dim3(4, 8, 32), 256, 0, stream>>>(
        S, v, ho, nullptr, nullptr, nullptr, 1.f,
        1024, 512, 1024, 1024, 1024, 512, 1024LL * 1024, 512 * 1024, 1024 * 512);
    // out (d,s) = WpT @ h_out^T + bp + x : M=d=512, N=s=1024, K=c=512, fp32
    nt_gemm<1, 0, 1><<<dim3(8, 4, 32), 256, 0, stream>>>(
        WpT, ho, out, bp, nullptr, x, 1.f,
        512, 1024, 512, 512, 512, 1024, 0, 1024 * 512, 512LL * 1024);
}

// Round 2
// 301.577 us; speedup vs baseline: 2.7147x; 2.7147x over previous
//
#include <hip/hip_runtime.h>
#include <hip/hip_bf16.h>
#include <math.h>

typedef __attribute__((ext_vector_type(8))) short bf16x8;
typedef __attribute__((ext_vector_type(4))) float f32x4;

typedef const __attribute__((address_space(1))) unsigned int guint;
typedef __attribute__((address_space(3))) unsigned int luint;

static __device__ __forceinline__ short f2bf(float f) {
    union { float f; unsigned u; } a; a.f = f;
    unsigned r = 0x7FFFu + ((a.u >> 16) & 1u);
    return (short)((a.u + r) >> 16);
}
static __device__ __forceinline__ float bf2f(short s) {
    union { unsigned u; float f; } a;
    a.u = ((unsigned)(unsigned short)s) << 16;
    return a.f;
}

// ---------------------------------------------------------------------------
// Weight transpose: W (c,d) fp32 -> WT (d,c) bf16, 4 weights stacked in z.
// ---------------------------------------------------------------------------
__global__ __launch_bounds__(256)
void transpose_w(const float* __restrict__ w0, const float* __restrict__ w1,
                 const float* __restrict__ w2, const float* __restrict__ w3,
                 short* __restrict__ outT)
{
    __shared__ float ld[32][33];
    const float* W = (blockIdx.z == 0) ? w0 : (blockIdx.z == 1) ? w1
                   : (blockIdx.z == 2) ? w2 : w3;
    short* O = outT + (long long)blockIdx.z * 512 * 512;
    const int tx = threadIdx.x & 31, ty = threadIdx.x >> 5;
    const int c0 = blockIdx.y * 32, d0 = blockIdx.x * 32;
#pragma unroll
    for (int r = 0; r < 4; ++r)
        ld[ty + 8 * r][tx] = W[(long long)(c0 + ty + 8 * r) * 512 + d0 + tx];
    __syncthreads();
#pragma unroll
    for (int r = 0; r < 4; ++r)
        O[(long long)(d0 + ty + 8 * r) * 512 + c0 + tx] = f2bf(ld[tx][ty + 8 * r]);
}

// ---------------------------------------------------------------------------
// GroupNorm stats: one block per (b,g); group = 16 ch x 1024 spatial.
// ---------------------------------------------------------------------------
__global__ __launch_bounds__(256)
void gn_stats(const float* __restrict__ x, float2* __restrict__ stats)
{
    const int bg = blockIdx.x;
    const float4* p = reinterpret_cast<const float4*>(x + (long long)bg * 16384);
    float s = 0.f, ss = 0.f;
    for (int i = threadIdx.x; i < 4096; i += 256) {
        float4 v = p[i];
        s  += v.x + v.y + v.z + v.w;
        ss += v.x * v.x + v.y * v.y + v.z * v.z + v.w * v.w;
    }
    __shared__ float rs[256], rss[256];
    rs[threadIdx.x] = s; rss[threadIdx.x] = ss;
    __syncthreads();
    for (int o = 128; o > 0; o >>= 1) {
        if (threadIdx.x < o) { rs[threadIdx.x] += rs[threadIdx.x + o];
                               rss[threadIdx.x] += rss[threadIdx.x + o]; }
        __syncthreads();
    }
    if (threadIdx.x == 0) {
        float mean = rs[0] * (1.f / 16384.f);
        float var  = rss[0] * (1.f / 16384.f) - mean * mean;
        stats[bg] = make_float2(mean, rsqrtf(var + 1e-6f));
    }
}

// ---------------------------------------------------------------------------
// GroupNorm apply + transpose: x (b,c,s) fp32 -> hn (b,s,c) bf16.
// ---------------------------------------------------------------------------
__global__ __launch_bounds__(256)
void gn_apply_t(const float* __restrict__ x, const float2* __restrict__ stats,
                const float* __restrict__ gamma, const float* __restrict__ beta,
                short* __restrict__ hn)
{
    __shared__ short lds[32 * 520];
    const int t = threadIdx.x;
    const int s0 = blockIdx.x * 32;
    const int b  = blockIdx.y;
#pragma unroll
    for (int i = 0; i < 16; ++i) {
        int qi = t + 256 * i;
        int c = qi >> 3, sc = qi & 7;
        float4 v = *reinterpret_cast<const float4*>(
            x + ((long long)(b * 512 + c)) * 1024 + s0 + sc * 4);
        float2 st = stats[b * 32 + (c >> 4)];
        float ga = gamma[c], be = beta[c];
        float m = st.x, r = st.y;
        lds[(sc * 4 + 0) * 520 + c] = f2bf((v.x - m) * r * ga + be);
        lds[(sc * 4 + 1) * 520 + c] = f2bf((v.y - m) * r * ga + be);
        lds[(sc * 4 + 2) * 520 + c] = f2bf((v.z - m) * r * ga + be);
        lds[(sc * 4 + 3) * 520 + c] = f2bf((v.w - m) * r * ga + be);
    }
    __syncthreads();
#pragma unroll
    for (int i = 0; i < 8; ++i) {
        int p = t + 256 * i;
        int s = p >> 6, j = p & 63;
        float4 v = *reinterpret_cast<const float4*>(&lds[s * 520 + j * 8]);
        *reinterpret_cast<float4*>(
            hn + ((long long)(b * 1024 + s0 + s)) * 512 + j * 8) = v;
    }
}

// ---------------------------------------------------------------------------
// NT GEMM, m97 structure: global_load_lds(16B) staging into LINEAR LDS,
// 2-barrier K-loop, 128x128 tile, 4 waves, 16x16x32 bf16 MFMA.
// 1-D grid with XCD-aware remap: each XCD gets a contiguous (batch,tile)
// slice so a batch's panels stay L2-resident (per-batch WS is 2-3 MB < 4 MB).
// C[m,n] = (sum_k A[m,k]*B[n,k] + biasM[m] + biasN[n]) * scale (+resid, f32)
// ---------------------------------------------------------------------------
template<int BIAS_M, int BIAS_N, int RESID>
__global__ __launch_bounds__(256)
void nt_gemm(const short* __restrict__ A, const short* __restrict__ B,
             void* __restrict__ Cv,
             const float* __restrict__ biasM, const float* __restrict__ biasN,
             const float* __restrict__ resid,
             float scale, int K, int lda, int ldb, int ldc,
             long long sA, long long sB, long long sC,
             int tilesM, int tilesPerBatch)
{
    __shared__ short lsA[128 * 64];   // 16 KB, linear (global_load_lds dest)
    __shared__ short lsB[128 * 64];

    // XCD-aware remap: id -> (xcd = id%8) owns contiguous gid chunk
    const int id = blockIdx.x;
    const int chunk = gridDim.x >> 3;            // grid % 8 == 0 by launch
    const int gid = (id & 7) * chunk + (id >> 3);
    const int bz = gid / tilesPerBatch;
    const int tt = gid - bz * tilesPerBatch;
    const int m0 = (tt % tilesM) * 128;
    const int n0 = (tt / tilesM) * 128;

    const int t = threadIdx.x;
    const int lane = t & 63;
    const int w = t >> 6;
    const int wr = w >> 1, wc = w & 1;
    const int lr16 = lane & 15, lkg = lane >> 4;

    // staging map: wave w covers rows [32w,32w+32); lane l -> row +l/8,
    // col (l%8)*8 elems; 4 chunks of 8 rows each (1 KB per issue).
    const int srow = 32 * w + (lane >> 3);
    const int scol = (lane & 7) * 8;
    const short* gA = A + (long long)bz * sA + (long long)(m0 + srow) * lda + scol;
    const short* gB = B + (long long)bz * sB + (long long)(n0 + srow) * ldb + scol;

    f32x4 acc[4][4];
#pragma unroll
    for (int i = 0; i < 4; ++i)
#pragma unroll
        for (int j = 0; j < 4; ++j) acc[i][j] = (f32x4){0.f, 0.f, 0.f, 0.f};

    const int nk = K >> 6;
    for (int kt = 0; kt < nk; ++kt) {
        const short* ga = gA + kt * 64;
        const short* gb = gB + kt * 64;
#pragma unroll
        for (int c = 0; c < 4; ++c) {
            __builtin_amdgcn_global_load_lds(
                (guint*)(ga + (long long)(8 * c) * lda),
                (luint*)&lsA[(32 * w + 8 * c) * 64], 16, 0, 0);
            __builtin_amdgcn_global_load_lds(
                (guint*)(gb + (long long)(8 * c) * ldb),
                (luint*)&lsB[(32 * w + 8 * c) * 64], 16, 0, 0);
        }
        __syncthreads();   // compiler drains vmcnt(0) before barrier
#pragma unroll
        for (int ks = 0; ks < 2; ++ks) {
            bf16x8 af[4], bfr[4];
#pragma unroll
            for (int mi = 0; mi < 4; ++mi)
                af[mi] = *reinterpret_cast<const bf16x8*>(
                    &lsA[(wr * 64 + mi * 16 + lr16) * 64 + ks * 32 + lkg * 8]);
#pragma unroll
            for (int ni = 0; ni < 4; ++ni)
                bfr[ni] = *reinterpret_cast<const bf16x8*>(
                    &lsB[(wc * 64 + ni * 16 + lr16) * 64 + ks * 32 + lkg * 8]);
#pragma unroll
            for (int mi = 0; mi < 4; ++mi)
#pragma unroll
                for (int ni = 0; ni < 4; ++ni)
                    acc[mi][ni] = __builtin_amdgcn_mfma_f32_16x16x32_bf16(
                        af[mi], bfr[ni], acc[mi][ni], 0, 0, 0);
        }
        __syncthreads();
    }

    // epilogue: D layout col=lane&15, row=(lane>>4)*4+reg (m89-verified)
#pragma unroll
    for (int mi = 0; mi < 4; ++mi) {
#pragma unroll
        for (int ni = 0; ni < 4; ++ni) {
            const int col = n0 + wc * 64 + ni * 16 + lr16;
            float bn = 0.f;
            if (BIAS_N) bn = biasN[col];
#pragma unroll
            for (int j = 0; j < 4; ++j) {
                const int rrow = m0 + wr * 64 + mi * 16 + lkg * 4 + j;
                float v = acc[mi][ni][j];
                if (BIAS_M) v += biasM[rrow];
                if (BIAS_N) v += bn;
                v *= scale;
                const long long idx = (long long)rrow * ldc + col;
                if (RESID) {
                    float* Cf = (float*)Cv + (long long)bz * sC;
                    Cf[idx] = v + resid[(long long)bz * sC + idx];
                } else {
                    short* Cs = (short*)Cv + (long long)bz * sC;
                    Cs[idx] = f2bf(v);
                }
            }
        }
    }
}

// ---------------------------------------------------------------------------
// Row softmax over 1024 bf16, in place. One wave per row, 4 rows per block.
// ---------------------------------------------------------------------------
__global__ __launch_bounds__(256)
void softmax_rows(short* __restrict__ S)
{
    const int wave = threadIdx.x >> 6, lane = threadIdx.x & 63;
    const long long row = (long long)blockIdx.x * 4 + wave;
    short* p = S + row * 1024;
    bf16x8 h0 = *reinterpret_cast<bf16x8*>(p + lane * 8);
    bf16x8 h1 = *reinterpret_cast<bf16x8*>(p + 512 + lane * 8);
    float v[16];
#pragma unroll
    for (int j = 0; j < 8; ++j) { v[j] = bf2f(h0[j]); v[8 + j] = bf2f(h1[j]); }
    float m = -1e30f;
#pragma unroll
    for (int j = 0; j < 16; ++j) m = fmaxf(m, v[j]);
#pragma unroll
    for (int o = 32; o > 0; o >>= 1) m = fmaxf(m, __shfl_xor(m, o));
    float s = 0.f;
#pragma unroll
    for (int j = 0; j < 16; ++j) { v[j] = __expf(v[j] - m); s += v[j]; }
#pragma unroll
    for (int o = 32; o > 0; o >>= 1) s += __shfl_xor(s, o);
    const float inv = 1.f / s;
    bf16x8 o0, o1;
#pragma unroll
    for (int j = 0; j < 8; ++j) { o0[j] = f2bf(v[j] * inv); o1[j] = f2bf(v[8 + j] * inv); }
    *reinterpret_cast<bf16x8*>(p + lane * 8) = o0;
    *reinterpret_cast<bf16x8*>(p + 512 + lane * 8) = o1;
}

// ---------------------------------------------------------------------------
extern "C" void kernel_launch(void* const* d_in, const int* in_sizes, int n_in,
                              void* d_out, int out_size, void* d_ws, size_t ws_size,
                              hipStream_t stream)
{
    (void)in_sizes; (void)n_in; (void)out_size; (void)ws_size;
    const float* x     = (const float*)d_in[0];
    const float* gamma = (const float*)d_in[1];
    const float* beta  = (const float*)d_in[2];
    const float* Wq = (const float*)d_in[3];
    const float* bq = (const float*)d_in[4];
    const float* Wk = (const float*)d_in[5];
    const float* bk = (const float*)d_in[6];
    const float* Wv = (const float*)d_in[7];
    const float* bv = (const float*)d_in[8];
    const float* Wp = (const float*)d_in[9];
    const float* bp = (const float*)d_in[10];
    float* out = (float*)d_out;

    // Workspace layout (time-overlapped): ~162.1 MB
    //   [0,64M):   S/P (b,s,t) bf16; hn (b,s,c) bf16 in [0,32M) dies before
    //              S is written (last read: v-GEMM, before scores-GEMM).
    //   [64,96M):  q (b,s,c) bf16; reused as h_out after scores.
    //   [96,128M): k ; [128,160M): v (b,c,t) ; [160M..): WT (2MB) + stats
    char* ws = (char*)d_ws;
    short*  S  = (short*)ws;
    short*  hn = (short*)ws;
    short*  q  = (short*)(ws + (64LL << 20));
    short*  k  = (short*)(ws + (96LL << 20));
    short*  v  = (short*)(ws + (128LL << 20));
    short*  wT = (short*)(ws + (160LL << 20));
    float2* stats = (float2*)(ws + (162LL << 20));
    short*  ho = q;

    const short* WqT = wT;
    const short* WkT = wT + 512 * 512;
    const short* WvT = wT + 2 * 512 * 512;
    const short* WpT = wT + 3 * 512 * 512;

    transpose_w<<<dim3(16, 16, 4), 256, 0, stream>>>(Wq, Wk, Wv, Wp, wT);
    gn_stats<<<dim3(1024), 256, 0, stream>>>(x, stats);
    gn_apply_t<<<dim3(32, 32), 256, 0, stream>>>(x, stats, gamma, beta, hn);

    const float qscale = 0.044194173824159216f;  // 512^-0.5

    // q = (hn @ Wq + bq)*qscale : M=1024(s), N=512(d), K=512 -> 8x4=32 tiles
    nt_gemm<0, 1, 0><<<1024, 256, 0, stream>>>(
        hn, WqT, q, nullptr, bq, nullptr, qscale,
        512, 512, 512, 512, 1024 * 512, 0, 1024 * 512, 8, 32);
    // k = hn @ Wk + bk
    nt_gemm<0, 1, 0><<<1024, 256, 0, stream>>>(
        hn, WkT, k, nullptr, bk, nullptr, 1.f,
        512, 512, 512, 512, 1024 * 512, 0, 1024 * 512, 8, 32);
    // v (d,t) = WvT @ hn^T + bv : M=512(d), N=1024(t), K=512 -> 4x8=32 tiles
    nt_gemm<1, 0, 0><<<1024, 256, 0, stream>>>(
        WvT, hn, v, bv, nullptr, nullptr, 1.f,
        512, 512, 512, 1024, 0, 1024 * 512, 512 * 1024, 4, 32);
    // scores (s,t) = q @ k^T : M=N=1024, K=512 -> 8x8=64 tiles
    nt_gemm<0, 0, 0><<<2048, 256, 0, stream>>>(
        q, k, S, nullptr, nullptr, nullptr, 1.f,
        512, 512, 512, 1024, 1024 * 512, 1024 * 512, 1024LL * 1024, 8, 64);
    // P = softmax(S) rowwise, in place
    softmax_rows<<<dim3(8192), 256, 0, stream>>>(S);
    // h_out (s,c) = P @ v^T : M=1024(s), N=512(c), K=1024 -> 8x4=32 tiles
    nt_gemm<0, 0, 0><<<1024, 256, 0, stream>>>(
        S, v, ho, nullptr, nullptr, nullptr, 1.f,
        1024, 1024, 1024, 512, 1024LL * 1024, 512 * 1024, 1024 * 512, 8, 32);
    // out (d,s) = WpT @ h_out^T + bp + x : M=512(d), N=1024(s), K=512, f32
    nt_gemm<1, 0, 1><<<1024, 256, 0, stream>>>(
        WpT, ho, out, bp, nullptr, x, 1.f,
        512, 512, 512, 1024, 0, 1024 * 512, 512LL * 1024, 4, 32);
}